// Round 2
// 188.214 us; speedup vs baseline: 1.0633x; 1.0633x over previous
//
#include <hip/hip_runtime.h>

constexpr int DIM  = 33;
constexpr int DIM2 = DIM * DIM;        // 1089
constexpr int DIM3 = DIM * DIM * DIM;  // 35937
constexpr int HW    = 1024 * 1024;
constexpr int BATCH = 8;
constexpr int GROUPS_PER_IMG = HW / 4;     // 262144 float4-groups per channel plane
constexpr unsigned LDS_BYTES = DIM3 * 4;   // 143748 B (fits 160 KiB/CU)

static_assert(256 * 1024 == GROUPS_PER_IMG, "grid must cover one image exactly");

// native clang vector type — required by __builtin_nontemporal_store
typedef float f32x4 __attribute__((ext_vector_type(4)));

// ---------------------------------------------------------------------------
// Tiny prep kernel: quantize+pack the LUT once into workspace.
// One dword per texel: ch0 bits[9:0], ch1 bits[19:10], ch2 bits[29:20].
// ---------------------------------------------------------------------------
__global__ __launch_bounds__(256) void lut_pack_kernel(
    const float* __restrict__ lut, unsigned int* __restrict__ packed)
{
    int i = blockIdx.x * blockDim.x + threadIdx.x;
    if (i < DIM3) {
        float v0 = lut[i];
        float v1 = lut[DIM3 + i];
        float v2 = lut[2 * DIM3 + i];
        unsigned q0 = (unsigned)(fminf(fmaxf(v0, 0.0f), 1.0f) * 1023.0f + 0.5f);
        unsigned q1 = (unsigned)(fminf(fmaxf(v1, 0.0f), 1.0f) * 1023.0f + 0.5f);
        unsigned q2 = (unsigned)(fminf(fmaxf(v2, 0.0f), 1.0f) * 1023.0f + 0.5f);
        packed[i] = q0 | (q1 << 10) | (q2 << 20);
    }
}

// ---------------------------------------------------------------------------
// Per-pixel trilinear interpolation against the packed LDS LUT.
// Identical math/order to the verified 200µs version (absmax-preserving);
// (int)t == (int)floorf(t) for t>=0, and post-clamp-equivalent otherwise
// because frac is computed against the clamped index, as in the reference.
// ---------------------------------------------------------------------------
__device__ __forceinline__ void lut_px(const unsigned int* sLut,
                                       float r, float g, float b,
                                       float& out0, float& out1, float& out2)
{
    const float invbin = 32.0f / 1.000001f;   // 1/binsize
    const float dq = 1.0f / 1023.0f;

    float tr = r * invbin;
    float tg = g * invbin;
    float tb = b * invbin;

    int ri = (int)tr;
    int gi = (int)tg;
    int bi = (int)tb;
    ri = ri < 0 ? 0 : (ri > DIM - 2 ? DIM - 2 : ri);
    gi = gi < 0 ? 0 : (gi > DIM - 2 ? DIM - 2 : gi);
    bi = bi < 0 ? 0 : (bi > DIM - 2 ? DIM - 2 : bi);

    float rd = tr - (float)ri;
    float gd = tg - (float)gi;
    float bd = tb - (float)bi;

    int base = bi * DIM2 + gi * DIM + ri;

    // 8 corner texels from LDS (adjacent r-pairs -> ds_read2_b32)
    unsigned c000 = sLut[base];
    unsigned c001 = sLut[base + 1];
    unsigned c010 = sLut[base + DIM];
    unsigned c011 = sLut[base + DIM + 1];
    unsigned c100 = sLut[base + DIM2];
    unsigned c101 = sLut[base + DIM2 + 1];
    unsigned c110 = sLut[base + DIM2 + DIM];
    unsigned c111 = sLut[base + DIM2 + DIM + 1];

    float wr1 = rd, wr0 = 1.0f - rd;
    float wg1 = gd, wg0 = 1.0f - gd;
    float wb1 = bd, wb0 = 1.0f - bd;

    float w000 = wb0 * wg0 * wr0;
    float w001 = wb0 * wg0 * wr1;
    float w010 = wb0 * wg1 * wr0;
    float w011 = wb0 * wg1 * wr1;
    float w100 = wb1 * wg0 * wr0;
    float w101 = wb1 * wg0 * wr1;
    float w110 = wb1 * wg1 * wr0;
    float w111 = wb1 * wg1 * wr1;

    float a0 = w000 * (float)(c000 & 1023u) + w001 * (float)(c001 & 1023u)
             + w010 * (float)(c010 & 1023u) + w011 * (float)(c011 & 1023u)
             + w100 * (float)(c100 & 1023u) + w101 * (float)(c101 & 1023u)
             + w110 * (float)(c110 & 1023u) + w111 * (float)(c111 & 1023u);

    float a1 = w000 * (float)((c000 >> 10) & 1023u) + w001 * (float)((c001 >> 10) & 1023u)
             + w010 * (float)((c010 >> 10) & 1023u) + w011 * (float)((c011 >> 10) & 1023u)
             + w100 * (float)((c100 >> 10) & 1023u) + w101 * (float)((c101 >> 10) & 1023u)
             + w110 * (float)((c110 >> 10) & 1023u) + w111 * (float)((c111 >> 10) & 1023u);

    float a2 = w000 * (float)(c000 >> 20) + w001 * (float)(c001 >> 20)
             + w010 * (float)(c010 >> 20) + w011 * (float)(c011 >> 20)
             + w100 * (float)(c100 >> 20) + w101 * (float)(c101 >> 20)
             + w110 * (float)(c110 >> 20) + w111 * (float)(c111 >> 20);

    out0 = a0 * dq;
    out1 = a1 * dq;
    out2 = a2 * dq;
}

// ---------------------------------------------------------------------------
// Main kernel. grid*block == GROUPS_PER_IMG: each thread owns one float4
// pixel-group q and walks the 8 batch images, prefetching image b+1's input
// while computing image b (hides global-load latency under compute+gather).
// ---------------------------------------------------------------------------
template <bool PREPACKED>
__global__ __launch_bounds__(1024) void lut3d_apply_kernel(
    const unsigned int* __restrict__ plut,   // packed LUT in workspace (PREPACKED)
    const float* __restrict__ lut,           // raw LUT (fallback path)
    const float* __restrict__ x,             // (8, 3, 1024, 1024)
    float* __restrict__ out)                 // (8, 3, 1024, 1024)
{
    extern __shared__ unsigned int sLut[];   // DIM3 dwords

    if constexpr (PREPACKED) {
        // 143 KB coalesced dwordx4 copy (vs 431 KB + quantize in fallback)
        const uint4* p4 = reinterpret_cast<const uint4*>(plut);
        uint4* s4 = reinterpret_cast<uint4*>(sLut);
        for (int i = threadIdx.x; i < DIM3 / 4; i += 1024) s4[i] = p4[i];
        if (threadIdx.x == 0) sLut[DIM3 - 1] = plut[DIM3 - 1];
    } else {
        for (int i = threadIdx.x; i < DIM3; i += 1024) {
            float v0 = lut[i];
            float v1 = lut[DIM3 + i];
            float v2 = lut[2 * DIM3 + i];
            unsigned q0 = (unsigned)(fminf(fmaxf(v0, 0.0f), 1.0f) * 1023.0f + 0.5f);
            unsigned q1 = (unsigned)(fminf(fmaxf(v1, 0.0f), 1.0f) * 1023.0f + 0.5f);
            unsigned q2 = (unsigned)(fminf(fmaxf(v2, 0.0f), 1.0f) * 1023.0f + 0.5f);
            sLut[i] = q0 | (q1 << 10) | (q2 << 20);
        }
    }
    __syncthreads();

    const int q = blockIdx.x * blockDim.x + threadIdx.x;   // [0, GROUPS_PER_IMG)
    const float4* __restrict__ xp = reinterpret_cast<const float4*>(x);
    f32x4* __restrict__ op = reinterpret_cast<f32x4*>(out);

    // preload image 0
    float4 rv = xp[(size_t)0 * GROUPS_PER_IMG + q];
    float4 gv = xp[(size_t)1 * GROUPS_PER_IMG + q];
    float4 bv = xp[(size_t)2 * GROUPS_PER_IMG + q];

#pragma unroll 2
    for (int b = 0; b < BATCH; ++b) {
        // prefetch image b+1 (clamped on last iteration; redundant load is L1-hot)
        int bnext = (b + 1 < BATCH) ? (b + 1) : b;
        size_t nb = (size_t)bnext * 3 * GROUPS_PER_IMG + q;
        float4 rn = xp[nb];
        float4 gn = xp[nb + GROUPS_PER_IMG];
        float4 bn = xp[nb + 2 * GROUPS_PER_IMG];

        float rr[4] = {rv.x, rv.y, rv.z, rv.w};
        float gg[4] = {gv.x, gv.y, gv.z, gv.w};
        float bb[4] = {bv.x, bv.y, bv.z, bv.w};
        float o0[4], o1[4], o2[4];

#pragma unroll
        for (int i = 0; i < 4; ++i)
            lut_px(sLut, rr[i], gg[i], bb[i], o0[i], o1[i], o2[i]);

        size_t ob = (size_t)b * 3 * GROUPS_PER_IMG + q;
        // output is never re-read: non-temporal keeps L2/L3 for the input
        f32x4 v0 = {o0[0], o0[1], o0[2], o0[3]};
        f32x4 v1 = {o1[0], o1[1], o1[2], o1[3]};
        f32x4 v2 = {o2[0], o2[1], o2[2], o2[3]};
        __builtin_nontemporal_store(v0, &op[ob]);
        __builtin_nontemporal_store(v1, &op[ob + GROUPS_PER_IMG]);
        __builtin_nontemporal_store(v2, &op[ob + 2 * GROUPS_PER_IMG]);

        rv = rn; gv = gn; bv = bn;
    }
}

extern "C" void kernel_launch(void* const* d_in, const int* in_sizes, int n_in,
                              void* d_out, int out_size, void* d_ws, size_t ws_size,
                              hipStream_t stream) {
    const float* lut = (const float*)d_in[0];  // 3*33*33*33
    const float* x   = (const float*)d_in[1];  // 8*3*1024*1024
    float* out = (float*)d_out;

    // 140 KB LDS -> 1 block/CU; 1024 threads = 16 waves/CU; 256 blocks = 1/CU.
    if (ws_size >= (size_t)LDS_BYTES && d_ws != nullptr) {
        unsigned int* packed = (unsigned int*)d_ws;
        lut_pack_kernel<<<(DIM3 + 255) / 256, 256, 0, stream>>>(lut, packed);
        lut3d_apply_kernel<true><<<256, 1024, LDS_BYTES, stream>>>(packed, lut, x, out);
    } else {
        lut3d_apply_kernel<false><<<256, 1024, LDS_BYTES, stream>>>(nullptr, lut, x, out);
    }
}